// Round 5
// baseline (795.294 us; speedup 1.0000x reference)
//
#include <hip/hip_runtime.h>
#include <math.h>

#define N_NODESC 100000
#define N_EDGESC 1600000
#define E_TOT    1700000   // incl. self loops
#define IN_CH    500
#define KPAD     512
#define D1 64
#define H1C 8
#define D2 24
#define H2C 8
#define NBLK 391           // ceil(N_NODESC/256)
#define NBKT 391           // dst buckets of 256 nodes
#define EPB  4096          // edges per k_part block

typedef __attribute__((ext_vector_type(8))) short short8;
typedef __attribute__((ext_vector_type(4))) float f32x4;

__device__ inline short f2bf(float f) {            // RTNE fp32 -> bf16
    unsigned u = __float_as_uint(f);
    u += 0x7fffu + ((u >> 16) & 1u);
    return (short)(u >> 16);
}
// pack two fp32 -> two bf16 (round-half-away) in one perm
__device__ inline unsigned pkbf(float a, float b) {
    const unsigned ua = __float_as_uint(a) + 0x8000u;
    const unsigned ub = __float_as_uint(b) + 0x8000u;
    return __builtin_amdgcn_perm(ub, ua, 0x07060302u);  // lo16=a_bf, hi16=b_bf
}

// ================= degree histogram =================
__global__ __launch_bounds__(256) void k_hist(const int* __restrict__ ei,
                                              int* __restrict__ deg) {
    const int e = blockIdx.x * 256 + threadIdx.x;
    if (e >= E_TOT) return;
    const int d = (e < N_EDGESC) ? ei[N_EDGESC + e] : (e - N_EDGESC);
    atomicAdd(deg + d, 1);
}

__global__ __launch_bounds__(256) void k_bsum(const int* __restrict__ deg,
                                              int* __restrict__ bsum) {
    const int i = blockIdx.x * 256 + threadIdx.x;
    int v = (i < N_NODESC) ? deg[i] : 0;
#pragma unroll
    for (int m = 1; m < 64; m <<= 1) v += __shfl_xor(v, m, 64);
    __shared__ int ws[4];
    if ((threadIdx.x & 63) == 0) ws[threadIdx.x >> 6] = v;
    __syncthreads();
    if (threadIdx.x == 0) bsum[blockIdx.x] = ws[0] + ws[1] + ws[2] + ws[3];
}

__global__ __launch_bounds__(512) void k_bscan(const int* __restrict__ bsum,
                                               int* __restrict__ boff) {
    __shared__ int sm[512];
    const int t = threadIdx.x;
    const int v = (t < NBLK) ? bsum[t] : 0;
    sm[t] = v;
    __syncthreads();
    for (int d = 1; d < 512; d <<= 1) {
        int u = (t >= d) ? sm[t - d] : 0;
        __syncthreads();
        sm[t] += u;
        __syncthreads();
    }
    if (t < NBLK) boff[t] = sm[t] - v;   // exclusive
}

__global__ __launch_bounds__(256) void k_off(const int* __restrict__ deg,
                                             const int* __restrict__ boff,
                                             int* __restrict__ off,
                                             int* __restrict__ gcur) {
    __shared__ int sm[256];
    const int t = threadIdx.x;
    const int i = blockIdx.x * 256 + t;
    const int v = (i < N_NODESC) ? deg[i] : 0;
    sm[t] = v;
    __syncthreads();
    for (int d = 1; d < 256; d <<= 1) {
        int u = (t >= d) ? sm[t - d] : 0;
        __syncthreads();
        sm[t] += u;
        __syncthreads();
    }
    if (i < N_NODESC) {
        const int ex = boff[blockIdx.x] + sm[t] - v;
        off[i] = ex;
        if ((i & 255) == 0) gcur[i >> 8] = ex;   // bucket cursor init
    }
    if (i == 0) off[N_NODESC] = E_TOT;
}

// ================= phase A: partition edges into 391 dst-buckets =================
__global__ __launch_bounds__(256) void k_part(const int* __restrict__ ei,
                                              int* __restrict__ gcur,
                                              int2* __restrict__ tmp) {
    __shared__ int hist[NBKT];
    __shared__ int lbase[NBKT];
    const int t = threadIdx.x;
    const int e0 = blockIdx.x * EPB;
    for (int i = t; i < NBKT; i += 256) hist[i] = 0;
    __syncthreads();
    int se[16], de[16], mo[16];
#pragma unroll
    for (int i = 0; i < 16; i++) {
        const int e = e0 + i * 256 + t;
        int s = -1, d = 0;
        if (e < E_TOT) {
            if (e < N_EDGESC) { s = ei[e]; d = ei[N_EDGESC + e]; }
            else { s = d = e - N_EDGESC; }
        }
        se[i] = s; de[i] = d;
        mo[i] = (s >= 0) ? atomicAdd(&hist[d >> 8], 1) : 0;
    }
    __syncthreads();
    for (int i = t; i < NBKT; i += 256)
        lbase[i] = hist[i] ? atomicAdd(&gcur[i], hist[i]) : 0;
    __syncthreads();
#pragma unroll
    for (int i = 0; i < 16; i++) {
        if (se[i] >= 0)
            tmp[lbase[de[i] >> 8] + mo[i]] = make_int2(se[i], de[i]);
    }
}

// ================= phase B: within-bucket scatter to CSR =================
__global__ __launch_bounds__(256) void k_bucket(const int* __restrict__ off,
                                                const int2* __restrict__ tmp,
                                                int* __restrict__ srt) {
    __shared__ int lcur[256];
    const int nodeBase = blockIdx.x << 8;
    const int t = threadIdx.x;
    const int nNodes = min(256, N_NODESC - nodeBase);
    if (t < nNodes) lcur[t] = off[nodeBase + t];
    const int start = off[nodeBase];
    const int end = off[nodeBase + nNodes];
    __syncthreads();
    for (int k = start + t; k < end; k += 256) {
        const int2 p = tmp[k];
        const int pos = atomicAdd(&lcur[p.y - nodeBase], 1);
        srt[pos] = p.x;
    }
}

// ================= W1 -> bf16 transposed, K zero-padded to 512 =================
__global__ __launch_bounds__(256) void k_wprep(const float* __restrict__ W1,
                                               short* __restrict__ wT) {
    const int idx = blockIdx.x * 256 + threadIdx.x;   // 64*512 = 32768
    if (idx >= D1 * KPAD) return;
    const int n = idx >> 9, k = idx & (KPAD - 1);
    wT[idx] = (k < IN_CH) ? f2bf(W1[k * D1 + n]) : (short)0;
}

// ================= K1: xw1 = x @ W1 via bf16 MFMA, register-direct, no LDS =================
// 1 wave = 16 rows x 64 cols. A-frag loaded straight from x (32B contiguous per lane).
__global__ __launch_bounds__(256) void k_gemm1(const float* __restrict__ x,
                                               const short* __restrict__ wT,
                                               float* __restrict__ xw1) {
    const int t = threadIdx.x;
    const int lane = t & 63, wv = t >> 6;
    const int m = lane & 15, kg = lane >> 4;
    const int rowBase = blockIdx.x * 64 + wv * 16;
    const int row = rowBase + m;
    const bool rok = row < N_NODESC;
    const float* xr = x + (long)row * IN_CH;

    f32x4 acc[4];
#pragma unroll
    for (int nt = 0; nt < 4; nt++) acc[nt] = (f32x4){0.f, 0.f, 0.f, 0.f};

#pragma unroll 4
    for (int k0 = 0; k0 < KPAD; k0 += 32) {
        const int ka = k0 + kg * 8;
        const float4 z4 = make_float4(0.f, 0.f, 0.f, 0.f);
        const float4 va = (rok && ka < IN_CH)     ? *(const float4*)(xr + ka)     : z4;
        const float4 vb = (rok && ka + 4 < IN_CH) ? *(const float4*)(xr + ka + 4) : z4;
        union { unsigned u[4]; short8 s; } cv;
        cv.u[0] = pkbf(va.x, va.y);
        cv.u[1] = pkbf(va.z, va.w);
        cv.u[2] = pkbf(vb.x, vb.y);
        cv.u[3] = pkbf(vb.z, vb.w);
        short8 bf[4];
#pragma unroll
        for (int nt = 0; nt < 4; nt++)
            bf[nt] = *(const short8*)(wT + (nt * 16 + m) * KPAD + ka);
#pragma unroll
        for (int nt = 0; nt < 4; nt++)
            acc[nt] = __builtin_amdgcn_mfma_f32_16x16x32_bf16(cv.s, bf[nt], acc[nt], 0, 0, 0);
    }

    // C layout: row = kg*4 + j, col = nt*16 + m
#pragma unroll
    for (int j = 0; j < 4; j++) {
        const int rowo = rowBase + kg * 4 + j;
        if (rowo < N_NODESC) {
#pragma unroll
            for (int nt = 0; nt < 4; nt++)
                xw1[(long)rowo * D1 + nt * 16 + m] = acc[nt][j];
        }
    }
}

// ================= K2: attention logit projections, layer 1 =================
__global__ __launch_bounds__(256) void k_al1(const float* __restrict__ xw1,
                                             const float* __restrict__ a1s,
                                             const float* __restrict__ a1d,
                                             float* __restrict__ al1s,
                                             float* __restrict__ al1d) {
    const int gid = blockIdx.x * 256 + threadIdx.x;
    if (gid >= N_NODESC * H1C) return;
    const int n = gid >> 3, h = gid & 7;
    const float4* p = (const float4*)(xw1 + (long)n * D1 + h * 8);
    const float4 v0 = p[0], v1 = p[1];
    const float4* as = (const float4*)(a1s + h * 8);
    const float4 s0 = as[0], s1 = as[1];
    const float4* ad = (const float4*)(a1d + h * 8);
    const float4 d0 = ad[0], d1 = ad[1];
    al1s[gid] = v0.x * s0.x + v0.y * s0.y + v0.z * s0.z + v0.w * s0.w +
                v1.x * s1.x + v1.y * s1.y + v1.z * s1.z + v1.w * s1.w;
    al1d[gid] = v0.x * d0.x + v0.y * d0.y + v0.z * d0.z + v0.w * d0.w +
                v1.x * d1.x + v1.y * d1.y + v1.z * d1.z + v1.w * d1.w;
}

// ================= K3: gather-aggregate layer 1 =================
__global__ __launch_bounds__(256) void k_gat1(const int* __restrict__ off,
                                              const int* __restrict__ srt_src,
                                              const float* __restrict__ al1s,
                                              const float* __restrict__ al1d,
                                              const float* __restrict__ xw1,
                                              const float* __restrict__ b1,
                                              float* __restrict__ hmid) {
    const int tid = threadIdx.x;
    const int lane = tid & 63;
    const int wid = tid >> 6;
    const int n = blockIdx.x * 4 + wid;   // N_NODESC % 4 == 0
    const int esub = lane >> 4;
    const int q = lane & 15;
    const int h = q >> 1;

    const float ald = al1d[n * 8 + h];
    const int kend = off[n + 1];

    float4 acc = make_float4(0.f, 0.f, 0.f, 0.f);
    float ssum = 0.f;
    for (int k = off[n] + esub; k < kend; k += 4) {
        const int s = srt_src[k];
        float ev = al1s[s * 8 + h] + ald;
        ev = ev > 0.f ? ev : 0.2f * ev;
        const float ex = expf(ev);
        const float4 v = *(const float4*)(xw1 + (long)s * D1 + q * 4);
        acc.x += ex * v.x; acc.y += ex * v.y; acc.z += ex * v.z; acc.w += ex * v.w;
        ssum += ex;
    }
#pragma unroll
    for (int m = 16; m < 64; m <<= 1) {
        acc.x += __shfl_xor(acc.x, m, 64);
        acc.y += __shfl_xor(acc.y, m, 64);
        acc.z += __shfl_xor(acc.z, m, 64);
        acc.w += __shfl_xor(acc.w, m, 64);
        ssum  += __shfl_xor(ssum,  m, 64);
    }
    if (esub == 0) {
        const float inv = 1.0f / (ssum + 1e-16f);
        const float4 bb = *(const float4*)(b1 + q * 4);
        float4 r;
        r.x = acc.x * inv + bb.x; r.x = r.x > 0.f ? r.x : expm1f(r.x);
        r.y = acc.y * inv + bb.y; r.y = r.y > 0.f ? r.y : expm1f(r.y);
        r.z = acc.z * inv + bb.z; r.z = r.z > 0.f ? r.z : expm1f(r.z);
        r.w = acc.w * inv + bb.w; r.w = r.w > 0.f ? r.w : expm1f(r.w);
        *(float4*)(hmid + (long)n * D1 + q * 4) = r;
    }
}

// ================= K4: xw2 = hmid @ W2, al2 projections =================
__global__ __launch_bounds__(256) void k_mid2(const float* __restrict__ hmid,
                                              const float* __restrict__ W2,
                                              const float* __restrict__ a2s,
                                              const float* __restrict__ a2d,
                                              float* __restrict__ xw2,
                                              float* __restrict__ al2s,
                                              float* __restrict__ al2d) {
    __shared__ float w2s[D1 * D2];
    for (int i = threadIdx.x; i < D1 * D2; i += 256) w2s[i] = W2[i];
    __syncthreads();
    const int n = blockIdx.x * 256 + threadIdx.x;
    if (n >= N_NODESC) return;

    float o[D2];
#pragma unroll
    for (int j = 0; j < D2; j++) o[j] = 0.f;
#pragma unroll
    for (int c4 = 0; c4 < D1; c4 += 4) {
        const float4 hv = *(const float4*)(hmid + (long)n * D1 + c4);
        const float* wr = w2s + c4 * D2;
#pragma unroll
        for (int j = 0; j < D2; j++) {
            o[j] += hv.x * wr[j] + hv.y * wr[D2 + j] + hv.z * wr[2 * D2 + j] + hv.w * wr[3 * D2 + j];
        }
    }
#pragma unroll
    for (int j = 0; j < D2; j++) xw2[(long)n * D2 + j] = o[j];
#pragma unroll
    for (int hh = 0; hh < 8; hh++) {
        al2s[n * 8 + hh] = o[hh * 3] * a2s[hh * 3] + o[hh * 3 + 1] * a2s[hh * 3 + 1] + o[hh * 3 + 2] * a2s[hh * 3 + 2];
        al2d[n * 8 + hh] = o[hh * 3] * a2d[hh * 3] + o[hh * 3 + 1] * a2d[hh * 3 + 1] + o[hh * 3 + 2] * a2d[hh * 3 + 2];
    }
}

// ================= K5: gather-aggregate layer 2 + head-mean + softmax =================
__global__ __launch_bounds__(256) void k_gat2(const int* __restrict__ off,
                                              const int* __restrict__ srt_src,
                                              const float* __restrict__ al2s,
                                              const float* __restrict__ al2d,
                                              const float* __restrict__ xw2,
                                              const float* __restrict__ b2,
                                              float* __restrict__ out) {
    __shared__ float sm[4][24];
    const int tid = threadIdx.x;
    const int lane = tid & 63;
    const int wid = tid >> 6;
    const int n = blockIdx.x * 4 + wid;
    const int esub = lane / 24;          // 0,1,2
    const int j = lane - esub * 24;
    const int h = j / 3;

    float acc = 0.f, ssum = 0.f;
    if (esub < 2) {
        const float ald = al2d[n * 8 + h];
        const int kend = off[n + 1];
        for (int k = off[n] + esub; k < kend; k += 2) {
            const int s = srt_src[k];
            float ev = al2s[s * 8 + h] + ald;
            ev = ev > 0.f ? ev : 0.2f * ev;
            const float ex = expf(ev);
            acc += ex * xw2[(long)s * D2 + j];
            ssum += ex;
        }
    }
    acc  += __shfl_down(acc, 24, 64);
    ssum += __shfl_down(ssum, 24, 64);
    if (lane < 24) sm[wid][j] = acc / (ssum + 1e-16f);
    __syncthreads();
    float lg = 0.f;
    if (lane < 3) {
#pragma unroll
        for (int hh = 0; hh < 8; hh++) lg += sm[wid][hh * 3 + lane];
        lg = lg * 0.125f + b2[lane];
    }
    const float l0 = __shfl(lg, 0, 64);
    const float l1 = __shfl(lg, 1, 64);
    const float l2 = __shfl(lg, 2, 64);
    if (lane < 3) {
        const float m = fmaxf(l0, fmaxf(l1, l2));
        const float denom = expf(l0 - m) + expf(l1 - m) + expf(l2 - m);
        out[(long)n * 3 + lane] = expf(lg - m) / denom;
    }
}

extern "C" void kernel_launch(void* const* d_in, const int* in_sizes, int n_in,
                              void* d_out, int out_size, void* d_ws, size_t ws_size,
                              hipStream_t stream) {
    const float* x   = (const float*)d_in[0];
    const float* W1  = (const float*)d_in[1];
    const float* a1s = (const float*)d_in[2];
    const float* a1d = (const float*)d_in[3];
    const float* b1  = (const float*)d_in[4];
    const float* W2  = (const float*)d_in[5];
    const float* a2s = (const float*)d_in[6];
    const float* a2d = (const float*)d_in[7];
    const float* b2  = (const float*)d_in[8];
    const int*   ei  = (const int*)d_in[9];
    float* out = (float*)d_out;

    float* ws   = (float*)d_ws;
    float* xw1  = ws;                  // 6,400,000
    float* al1s = xw1  + 6400000;      //   800,000
    float* al1d = al1s + 800000;       //   800,000
    float* hmid = al1d + 800000;       // 6,400,000  (tmp overlays this before k_gat1)
    float* xw2  = hmid + 6400000;      // 2,400,000
    float* al2s = xw2  + 2400000;      //   800,000
    float* al2d = al2s + 800000;       //   800,000
    int* deg    = (int*)(al2d + 800000);   //   100,000
    int* off    = deg + 100000;            //   100,001
    int* gcur   = off + 100001;            //   NBKT
    int* srt    = gcur + NBKT;             // 1,700,000
    int* bsum   = srt + 1700000;           //   NBLK
    int* boff   = bsum + NBLK;             //   NBLK
    short* wT   = (short*)(boff + NBLK);   //   64*512 halfs
    int2* tmp   = (int2*)hmid;             // 1,700,000 int2 (13.6 MB < 25.6 MB)

    hipMemsetAsync(deg, 0, (size_t)N_NODESC * sizeof(int), stream);

    const int EB = (E_TOT + 255) / 256;
    k_hist<<<EB, 256, 0, stream>>>(ei, deg);
    k_bsum<<<NBLK, 256, 0, stream>>>(deg, bsum);
    k_bscan<<<1, 512, 0, stream>>>(bsum, boff);
    k_off<<<NBLK, 256, 0, stream>>>(deg, boff, off, gcur);
    k_part<<<(E_TOT + EPB - 1) / EPB, 256, 0, stream>>>(ei, gcur, tmp);
    k_bucket<<<NBKT, 256, 0, stream>>>(off, tmp, srt);

    k_wprep<<<(D1 * KPAD + 255) / 256, 256, 0, stream>>>(W1, wT);
    k_gemm1<<<(N_NODESC + 63) / 64, 256, 0, stream>>>(x, wT, xw1);
    k_al1<<<(N_NODESC * H1C + 255) / 256, 256, 0, stream>>>(xw1, a1s, a1d, al1s, al1d);
    k_gat1<<<N_NODESC / 4, 256, 0, stream>>>(off, srt, al1s, al1d, xw1, b1, hmid);
    k_mid2<<<(N_NODESC + 255) / 256, 256, 0, stream>>>(hmid, W2, a2s, a2d, xw2, al2s, al2d);
    k_gat2<<<N_NODESC / 4, 256, 0, stream>>>(off, srt, al2s, al2d, xw2, b2, out);
}

// Round 6
// 636.091 us; speedup vs baseline: 1.2503x; 1.2503x over previous
//
#include <hip/hip_runtime.h>
#include <math.h>

#define N_NODESC 100000
#define N_EDGESC 1600000
#define E_TOT    1700000   // incl. self loops
#define IN_CH    500
#define KPAD     512
#define D1 64
#define H1C 8
#define D2 24
#define H2C 8
#define NBLK 391           // ceil(N_NODESC/256)
#define NBKT 391           // dst buckets of 256 nodes
#define EPB  4096          // edges per k_part block

typedef __attribute__((ext_vector_type(8))) short short8;
typedef __attribute__((ext_vector_type(4))) float f32x4;

__device__ inline short f2bf(float f) {            // RTNE fp32 -> bf16
    unsigned u = __float_as_uint(f);
    u += 0x7fffu + ((u >> 16) & 1u);
    return (short)(u >> 16);
}
// pack two fp32 -> two bf16 (round-half-away) in one perm
__device__ inline unsigned pkbf(float a, float b) {
    const unsigned ua = __float_as_uint(a) + 0x8000u;
    const unsigned ub = __float_as_uint(b) + 0x8000u;
    return __builtin_amdgcn_perm(ub, ua, 0x07060302u);  // lo16=a_bf, hi16=b_bf
}

// ================= degree histogram =================
__global__ __launch_bounds__(256) void k_hist(const int* __restrict__ ei,
                                              int* __restrict__ deg) {
    const int e = blockIdx.x * 256 + threadIdx.x;
    if (e >= E_TOT) return;
    const int d = (e < N_EDGESC) ? ei[N_EDGESC + e] : (e - N_EDGESC);
    atomicAdd(deg + d, 1);
}

__global__ __launch_bounds__(256) void k_bsum(const int* __restrict__ deg,
                                              int* __restrict__ bsum) {
    const int i = blockIdx.x * 256 + threadIdx.x;
    int v = (i < N_NODESC) ? deg[i] : 0;
#pragma unroll
    for (int m = 1; m < 64; m <<= 1) v += __shfl_xor(v, m, 64);
    __shared__ int ws[4];
    if ((threadIdx.x & 63) == 0) ws[threadIdx.x >> 6] = v;
    __syncthreads();
    if (threadIdx.x == 0) bsum[blockIdx.x] = ws[0] + ws[1] + ws[2] + ws[3];
}

__global__ __launch_bounds__(512) void k_bscan(const int* __restrict__ bsum,
                                               int* __restrict__ boff) {
    __shared__ int sm[512];
    const int t = threadIdx.x;
    const int v = (t < NBLK) ? bsum[t] : 0;
    sm[t] = v;
    __syncthreads();
    for (int d = 1; d < 512; d <<= 1) {
        int u = (t >= d) ? sm[t - d] : 0;
        __syncthreads();
        sm[t] += u;
        __syncthreads();
    }
    if (t < NBLK) boff[t] = sm[t] - v;   // exclusive
}

__global__ __launch_bounds__(256) void k_off(const int* __restrict__ deg,
                                             const int* __restrict__ boff,
                                             int* __restrict__ off,
                                             int* __restrict__ gcur) {
    __shared__ int sm[256];
    const int t = threadIdx.x;
    const int i = blockIdx.x * 256 + t;
    const int v = (i < N_NODESC) ? deg[i] : 0;
    sm[t] = v;
    __syncthreads();
    for (int d = 1; d < 256; d <<= 1) {
        int u = (t >= d) ? sm[t - d] : 0;
        __syncthreads();
        sm[t] += u;
        __syncthreads();
    }
    if (i < N_NODESC) {
        const int ex = boff[blockIdx.x] + sm[t] - v;
        off[i] = ex;
        if ((i & 255) == 0) gcur[i >> 8] = ex;   // bucket cursor init
    }
    if (i == 0) off[N_NODESC] = E_TOT;
}

// ================= phase A: partition edges into 391 dst-buckets =================
__global__ __launch_bounds__(256) void k_part(const int* __restrict__ ei,
                                              int* __restrict__ gcur,
                                              int2* __restrict__ tmp) {
    __shared__ int hist[NBKT];
    __shared__ int lbase[NBKT];
    const int t = threadIdx.x;
    const int e0 = blockIdx.x * EPB;
    for (int i = t; i < NBKT; i += 256) hist[i] = 0;
    __syncthreads();
    int se[16], de[16], mo[16];
#pragma unroll
    for (int i = 0; i < 16; i++) {
        const int e = e0 + i * 256 + t;
        int s = -1, d = 0;
        if (e < E_TOT) {
            if (e < N_EDGESC) { s = ei[e]; d = ei[N_EDGESC + e]; }
            else { s = d = e - N_EDGESC; }
        }
        se[i] = s; de[i] = d;
        mo[i] = (s >= 0) ? atomicAdd(&hist[d >> 8], 1) : 0;
    }
    __syncthreads();
    for (int i = t; i < NBKT; i += 256)
        lbase[i] = hist[i] ? atomicAdd(&gcur[i], hist[i]) : 0;
    __syncthreads();
#pragma unroll
    for (int i = 0; i < 16; i++) {
        if (se[i] >= 0)
            tmp[lbase[de[i] >> 8] + mo[i]] = make_int2(se[i], de[i]);
    }
}

// ================= phase B: within-bucket scatter to CSR =================
__global__ __launch_bounds__(256) void k_bucket(const int* __restrict__ off,
                                                const int2* __restrict__ tmp,
                                                int* __restrict__ srt) {
    __shared__ int lcur[256];
    const int nodeBase = blockIdx.x << 8;
    const int t = threadIdx.x;
    const int nNodes = min(256, N_NODESC - nodeBase);
    if (t < nNodes) lcur[t] = off[nodeBase + t];
    const int start = off[nodeBase];
    const int end = off[nodeBase + nNodes];
    __syncthreads();
    for (int k = start + t; k < end; k += 256) {
        const int2 p = tmp[k];
        const int pos = atomicAdd(&lcur[p.y - nodeBase], 1);
        srt[pos] = p.x;
    }
}

// ================= W1 -> bf16 transposed, K zero-padded to 512 =================
__global__ __launch_bounds__(256) void k_wprep(const float* __restrict__ W1,
                                               short* __restrict__ wT) {
    const int idx = blockIdx.x * 256 + threadIdx.x;   // 64*512 = 32768
    if (idx >= D1 * KPAD) return;
    const int n = idx >> 9, k = idx & (KPAD - 1);
    wT[idx] = (k < IN_CH) ? f2bf(W1[k * D1 + n]) : (short)0;
}

// ================= K1: xw1 = x @ W1 via bf16 MFMA =================
// Block = 32 rows x FULL K. Staging: 8 thr/row read consecutive float4s ->
// fully coalesced (8 x 128B contiguous segments per wave inst). ONE barrier
// per block; K-loop is pure LDS + L1-resident wT. LDS stride 520 halfs ->
// A-frag banks 4*(row+kg) mod 32: uniform 8 words/bank = b128 data floor.
__global__ __launch_bounds__(256) void k_gemm1(const float* __restrict__ x,
                                               const short* __restrict__ wT,
                                               float* __restrict__ xw1) {
    __shared__ short xs[32 * 520];
    const int t = threadIdx.x;
    const int rowBase = blockIdx.x * 32;        // 3125 * 32 == 100000 exactly
    const int r = t >> 3, j = t & 7;
    const float* xr = x + (long)(rowBase + r) * IN_CH;
    short* xrow = xs + r * 520;
#pragma unroll
    for (int i = 0; i < 16; i++) {
        const int c = j + i * 8;                 // float4 index, 125 per row
        if (c < 125) {
            const float4 v = *(const float4*)(xr + c * 4);
            const unsigned lo = pkbf(v.x, v.y);
            const unsigned hi = pkbf(v.z, v.w);
            *(uint2*)(xrow + c * 4) = make_uint2(lo, hi);
        }
    }
    if (j < 6) *(unsigned*)(xrow + 500 + j * 2) = 0u;   // zero halfs 500..511
    __syncthreads();

    const int lane = t & 63, wv = t >> 6;
    const int m = lane & 15, kg = lane >> 4;
    f32x4 acc[2];
    acc[0] = (f32x4){0.f, 0.f, 0.f, 0.f};
    acc[1] = (f32x4){0.f, 0.f, 0.f, 0.f};
    const short* wcol = wT + (wv * 16 + m) * KPAD;
#pragma unroll
    for (int k0 = 0; k0 < KPAD; k0 += 32) {
        const short8 bf = *(const short8*)(wcol + k0 + kg * 8);
#pragma unroll
        for (int mf = 0; mf < 2; mf++) {
            const short8 af = *(const short8*)(xs + (mf * 16 + m) * 520 + k0 + kg * 8);
            acc[mf] = __builtin_amdgcn_mfma_f32_16x16x32_bf16(af, bf, acc[mf], 0, 0, 0);
        }
    }
    // C layout: row = kg*4 + jj (within 16-row frag), col = wv*16 + m
#pragma unroll
    for (int mf = 0; mf < 2; mf++) {
#pragma unroll
        for (int jj = 0; jj < 4; jj++) {
            const int row = rowBase + mf * 16 + kg * 4 + jj;
            xw1[(long)row * D1 + wv * 16 + m] = acc[mf][jj];
        }
    }
}

// ================= K2: attention logit projections, layer 1 =================
__global__ __launch_bounds__(256) void k_al1(const float* __restrict__ xw1,
                                             const float* __restrict__ a1s,
                                             const float* __restrict__ a1d,
                                             float* __restrict__ al1s,
                                             float* __restrict__ al1d) {
    const int gid = blockIdx.x * 256 + threadIdx.x;
    if (gid >= N_NODESC * H1C) return;
    const int n = gid >> 3, h = gid & 7;
    const float4* p = (const float4*)(xw1 + (long)n * D1 + h * 8);
    const float4 v0 = p[0], v1 = p[1];
    const float4* as = (const float4*)(a1s + h * 8);
    const float4 s0 = as[0], s1 = as[1];
    const float4* ad = (const float4*)(a1d + h * 8);
    const float4 d0 = ad[0], d1 = ad[1];
    al1s[gid] = v0.x * s0.x + v0.y * s0.y + v0.z * s0.z + v0.w * s0.w +
                v1.x * s1.x + v1.y * s1.y + v1.z * s1.z + v1.w * s1.w;
    al1d[gid] = v0.x * d0.x + v0.y * d0.y + v0.z * d0.z + v0.w * d0.w +
                v1.x * d1.x + v1.y * d1.y + v1.z * d1.z + v1.w * d1.w;
}

// ================= K3: gather-aggregate layer 1 =================
__global__ __launch_bounds__(256) void k_gat1(const int* __restrict__ off,
                                              const int* __restrict__ srt_src,
                                              const float* __restrict__ al1s,
                                              const float* __restrict__ al1d,
                                              const float* __restrict__ xw1,
                                              const float* __restrict__ b1,
                                              float* __restrict__ hmid) {
    const int tid = threadIdx.x;
    const int lane = tid & 63;
    const int wid = tid >> 6;
    const int n = blockIdx.x * 4 + wid;   // N_NODESC % 4 == 0
    const int esub = lane >> 4;
    const int q = lane & 15;
    const int h = q >> 1;

    const float ald = al1d[n * 8 + h];
    const int kend = off[n + 1];

    float4 acc = make_float4(0.f, 0.f, 0.f, 0.f);
    float ssum = 0.f;
    for (int k = off[n] + esub; k < kend; k += 4) {
        const int s = srt_src[k];
        float ev = al1s[s * 8 + h] + ald;
        ev = ev > 0.f ? ev : 0.2f * ev;
        const float ex = expf(ev);
        const float4 v = *(const float4*)(xw1 + (long)s * D1 + q * 4);
        acc.x += ex * v.x; acc.y += ex * v.y; acc.z += ex * v.z; acc.w += ex * v.w;
        ssum += ex;
    }
#pragma unroll
    for (int m = 16; m < 64; m <<= 1) {
        acc.x += __shfl_xor(acc.x, m, 64);
        acc.y += __shfl_xor(acc.y, m, 64);
        acc.z += __shfl_xor(acc.z, m, 64);
        acc.w += __shfl_xor(acc.w, m, 64);
        ssum  += __shfl_xor(ssum,  m, 64);
    }
    if (esub == 0) {
        const float inv = 1.0f / (ssum + 1e-16f);
        const float4 bb = *(const float4*)(b1 + q * 4);
        float4 r;
        r.x = acc.x * inv + bb.x; r.x = r.x > 0.f ? r.x : expm1f(r.x);
        r.y = acc.y * inv + bb.y; r.y = r.y > 0.f ? r.y : expm1f(r.y);
        r.z = acc.z * inv + bb.z; r.z = r.z > 0.f ? r.z : expm1f(r.z);
        r.w = acc.w * inv + bb.w; r.w = r.w > 0.f ? r.w : expm1f(r.w);
        *(float4*)(hmid + (long)n * D1 + q * 4) = r;
    }
}

// ================= K4: xw2 = hmid @ W2, al2 projections =================
__global__ __launch_bounds__(256) void k_mid2(const float* __restrict__ hmid,
                                              const float* __restrict__ W2,
                                              const float* __restrict__ a2s,
                                              const float* __restrict__ a2d,
                                              float* __restrict__ xw2,
                                              float* __restrict__ al2s,
                                              float* __restrict__ al2d) {
    __shared__ float w2s[D1 * D2];
    for (int i = threadIdx.x; i < D1 * D2; i += 256) w2s[i] = W2[i];
    __syncthreads();
    const int n = blockIdx.x * 256 + threadIdx.x;
    if (n >= N_NODESC) return;

    float o[D2];
#pragma unroll
    for (int j = 0; j < D2; j++) o[j] = 0.f;
#pragma unroll
    for (int c4 = 0; c4 < D1; c4 += 4) {
        const float4 hv = *(const float4*)(hmid + (long)n * D1 + c4);
        const float* wr = w2s + c4 * D2;
#pragma unroll
        for (int j = 0; j < D2; j++) {
            o[j] += hv.x * wr[j] + hv.y * wr[D2 + j] + hv.z * wr[2 * D2 + j] + hv.w * wr[3 * D2 + j];
        }
    }
#pragma unroll
    for (int j = 0; j < D2; j++) xw2[(long)n * D2 + j] = o[j];
#pragma unroll
    for (int hh = 0; hh < 8; hh++) {
        al2s[n * 8 + hh] = o[hh * 3] * a2s[hh * 3] + o[hh * 3 + 1] * a2s[hh * 3 + 1] + o[hh * 3 + 2] * a2s[hh * 3 + 2];
        al2d[n * 8 + hh] = o[hh * 3] * a2d[hh * 3] + o[hh * 3 + 1] * a2d[hh * 3 + 1] + o[hh * 3 + 2] * a2d[hh * 3 + 2];
    }
}

// ================= K5: gather-aggregate layer 2 + head-mean + softmax =================
__global__ __launch_bounds__(256) void k_gat2(const int* __restrict__ off,
                                              const int* __restrict__ srt_src,
                                              const float* __restrict__ al2s,
                                              const float* __restrict__ al2d,
                                              const float* __restrict__ xw2,
                                              const float* __restrict__ b2,
                                              float* __restrict__ out) {
    __shared__ float sm[4][24];
    const int tid = threadIdx.x;
    const int lane = tid & 63;
    const int wid = tid >> 6;
    const int n = blockIdx.x * 4 + wid;
    const int esub = lane / 24;          // 0,1,2
    const int j = lane - esub * 24;
    const int h = j / 3;

    float acc = 0.f, ssum = 0.f;
    if (esub < 2) {
        const float ald = al2d[n * 8 + h];
        const int kend = off[n + 1];
        for (int k = off[n] + esub; k < kend; k += 2) {
            const int s = srt_src[k];
            float ev = al2s[s * 8 + h] + ald;
            ev = ev > 0.f ? ev : 0.2f * ev;
            const float ex = expf(ev);
            acc += ex * xw2[(long)s * D2 + j];
            ssum += ex;
        }
    }
    acc  += __shfl_down(acc, 24, 64);
    ssum += __shfl_down(ssum, 24, 64);
    if (lane < 24) sm[wid][j] = acc / (ssum + 1e-16f);
    __syncthreads();
    float lg = 0.f;
    if (lane < 3) {
#pragma unroll
        for (int hh = 0; hh < 8; hh++) lg += sm[wid][hh * 3 + lane];
        lg = lg * 0.125f + b2[lane];
    }
    const float l0 = __shfl(lg, 0, 64);
    const float l1 = __shfl(lg, 1, 64);
    const float l2 = __shfl(lg, 2, 64);
    if (lane < 3) {
        const float m = fmaxf(l0, fmaxf(l1, l2));
        const float denom = expf(l0 - m) + expf(l1 - m) + expf(l2 - m);
        out[(long)n * 3 + lane] = expf(lg - m) / denom;
    }
}

extern "C" void kernel_launch(void* const* d_in, const int* in_sizes, int n_in,
                              void* d_out, int out_size, void* d_ws, size_t ws_size,
                              hipStream_t stream) {
    const float* x   = (const float*)d_in[0];
    const float* W1  = (const float*)d_in[1];
    const float* a1s = (const float*)d_in[2];
    const float* a1d = (const float*)d_in[3];
    const float* b1  = (const float*)d_in[4];
    const float* W2  = (const float*)d_in[5];
    const float* a2s = (const float*)d_in[6];
    const float* a2d = (const float*)d_in[7];
    const float* b2  = (const float*)d_in[8];
    const int*   ei  = (const int*)d_in[9];
    float* out = (float*)d_out;

    float* ws   = (float*)d_ws;
    float* xw1  = ws;                  // 6,400,000
    float* al1s = xw1  + 6400000;      //   800,000
    float* al1d = al1s + 800000;       //   800,000
    float* hmid = al1d + 800000;       // 6,400,000  (tmp overlays this before k_gat1)
    float* xw2  = hmid + 6400000;      // 2,400,000
    float* al2s = xw2  + 2400000;      //   800,000
    float* al2d = al2s + 800000;       //   800,000
    int* deg    = (int*)(al2d + 800000);   //   100,000
    int* off    = deg + 100000;            //   100,001
    int* gcur   = off + 100001;            //   NBKT
    int* srt    = gcur + NBKT;             // 1,700,000
    int* bsum   = srt + 1700000;           //   NBLK
    int* boff   = bsum + NBLK;             //   NBLK
    short* wT   = (short*)(boff + NBLK);   //   64*512 halfs
    int2* tmp   = (int2*)hmid;             // 1,700,000 int2 (13.6 MB < 25.6 MB)

    hipMemsetAsync(deg, 0, (size_t)N_NODESC * sizeof(int), stream);

    const int EB = (E_TOT + 255) / 256;
    k_hist<<<EB, 256, 0, stream>>>(ei, deg);
    k_bsum<<<NBLK, 256, 0, stream>>>(deg, bsum);
    k_bscan<<<1, 512, 0, stream>>>(bsum, boff);
    k_off<<<NBLK, 256, 0, stream>>>(deg, boff, off, gcur);
    k_part<<<(E_TOT + EPB - 1) / EPB, 256, 0, stream>>>(ei, gcur, tmp);
    k_bucket<<<NBKT, 256, 0, stream>>>(off, tmp, srt);

    k_wprep<<<(D1 * KPAD + 255) / 256, 256, 0, stream>>>(W1, wT);
    k_gemm1<<<N_NODESC / 32, 256, 0, stream>>>(x, wT, xw1);
    k_al1<<<(N_NODESC * H1C + 255) / 256, 256, 0, stream>>>(xw1, a1s, a1d, al1s, al1d);
    k_gat1<<<N_NODESC / 4, 256, 0, stream>>>(off, srt, al1s, al1d, xw1, b1, hmid);
    k_mid2<<<(N_NODESC + 255) / 256, 256, 0, stream>>>(hmid, W2, a2s, a2d, xw2, al2s, al2d);
    k_gat2<<<N_NODESC / 4, 256, 0, stream>>>(off, srt, al2s, al2d, xw2, b2, out);
}